// Round 15
// baseline (490.280 us; speedup 1.0000x reference)
//
#include <hip/hip_runtime.h>

#define NN 50000
#define NE 800000
#define DD 128
#define RR 8
#define MB (NN * RR)          // 400000 buckets keyed by (dst, r)
#define SCAN_BLK 2048
#define NBLK ((MB + SCAN_BLK - 1) / SCAN_BLK)   // 196

#define HT64 391              // 64-row tiles per half
#define HROWS (HT64 * 64)     // 25024 rows per half
#define SL32 ((size_t)NN * 32)   // elements per slice table

typedef __attribute__((ext_vector_type(8))) short short8;
typedef __attribute__((ext_vector_type(4))) float f32x4;

__device__ __forceinline__ unsigned short f2bf(float f)
{
    unsigned int u = __float_as_uint(f);
    u = (u + 0x7FFFu + ((u >> 16) & 1u)) >> 16;   // RNE
    return (unsigned short)u;
}
__device__ __forceinline__ float bflo(unsigned int p) { return __uint_as_float(p << 16); }
__device__ __forceinline__ float bfhi(unsigned int p) { return __uint_as_float(p & 0xFFFF0000u); }

// ---------------- count per (dst, relation); atomic return = edge rank ----------------
__global__ __launch_bounds__(256) void k_count(const int* __restrict__ ei,
                                               const int* __restrict__ et,
                                               int* __restrict__ cnt,
                                               unsigned short* __restrict__ rank16)
{
    int e = blockIdx.x * 256 + threadIdx.x;
    if (e < NE) {
        int r = et[e];
        int dst = ei[NE + e];
        int old = atomicAdd(&cnt[dst * RR + r], 1);
        rank16[e] = (unsigned short)old;
    }
}

// ---------------- exclusive scan over cnt -> off ----------------
__global__ __launch_bounds__(256) void k_scan1(const int* __restrict__ cnt,
                                               int* __restrict__ off,
                                               int* __restrict__ bsum)
{
    __shared__ int lds[256];
    int t = threadIdx.x;
    int base = blockIdx.x * SCAN_BLK + t * 8;
    int v[8], s = 0;
    #pragma unroll
    for (int j = 0; j < 8; j++) {
        int idx = base + j;
        v[j] = (idx < MB) ? cnt[idx] : 0;
        s += v[j];
    }
    lds[t] = s;
    __syncthreads();
    for (int d = 1; d < 256; d <<= 1) {
        int u = (t >= d) ? lds[t - d] : 0;
        __syncthreads();
        lds[t] += u;
        __syncthreads();
    }
    if (t == 255) bsum[blockIdx.x] = lds[255];
    int run = lds[t] - s;
    #pragma unroll
    for (int j = 0; j < 8; j++) {
        int idx = base + j;
        if (idx < MB) off[idx] = run;
        run += v[j];
    }
}

__global__ __launch_bounds__(256) void k_scan2(const int* __restrict__ bsum,
                                               int* __restrict__ carry)
{
    __shared__ int lds[256];
    int t = threadIdx.x;
    int s = (t < NBLK) ? bsum[t] : 0;
    lds[t] = s;
    __syncthreads();
    for (int d = 1; d < 256; d <<= 1) {
        int u = (t >= d) ? lds[t - d] : 0;
        __syncthreads();
        lds[t] += u;
        __syncthreads();
    }
    if (t < NBLK) carry[t] = lds[t] - s;
}

__global__ __launch_bounds__(256) void k_scan3(int* __restrict__ off,
                                               const int* __restrict__ carry)
{
    int c = carry[blockIdx.x];
    int base = blockIdx.x * SCAN_BLK + threadIdx.x * 8;
    #pragma unroll
    for (int j = 0; j < 8; j++) {
        int idx = base + j;
        if (idx < MB) off[idx] += c;
    }
    if (blockIdx.x == 0 && threadIdx.x == 0) off[MB] = NE;   // sentinel
}

// ---------------- place edges into CSR slots: NO atomics (rank precomputed) ----------------
__global__ __launch_bounds__(256) void k_place(const int* __restrict__ ei,
                                               const int* __restrict__ et,
                                               const int* __restrict__ off,
                                               const unsigned short* __restrict__ rank16,
                                               unsigned short* __restrict__ srt16)
{
    int e = blockIdx.x * 256 + threadIdx.x;
    if (e < NE) {
        int b = ei[NE + e] * RR + et[e];
        srt16[off[b] + (int)rank16[e]] = (unsigned short)ei[e];   // src < 50000 < 65536
    }
}

// ---------------- f32 -> bf16, SLICE-MAJOR: Xs[s][row][32] (contiguous 3.2MB tables) ----------------
__global__ __launch_bounds__(256) void k_tobf16s(const float* __restrict__ x,
                                                 unsigned short* __restrict__ Xs)
{
    int i = blockIdx.x * 256 + threadIdx.x;   // one float4 (4 cols) per thread
    if (i >= NN * 32) return;
    int row = i >> 5;
    int cq = i & 31;            // col-quad: cols 4*cq..4*cq+3
    float4 v = *(const float4*)(x + (size_t)row * 128 + cq * 4);
    uint2 o;
    o.x = (unsigned int)f2bf(v.x) | ((unsigned int)f2bf(v.y) << 16);
    o.y = (unsigned int)f2bf(v.z) | ((unsigned int)f2bf(v.w) << 16);
    int s = cq >> 3;
    *(uint2*)(Xs + (size_t)s * SL32 + (size_t)row * 32 + (cq & 7) * 4) = o;
}

// ---------------- weights: transpose + bf16: Wb[m][n][k] = src[m][k][n] ----------------
__global__ __launch_bounds__(256) void k_wconv(const float* __restrict__ W1,
                                               const float* __restrict__ root1,
                                               const float* __restrict__ W2,
                                               const float* __restrict__ root2,
                                               unsigned short* __restrict__ Wb)
{
    int e = blockIdx.x * 256 + threadIdx.x;
    if (e >= 18 * 16384) return;
    int m = e >> 14;
    int rem = e & 16383;
    int n = rem >> 7;
    int k = rem & 127;
    float v;
    if (m < 8)       v = W1[m * 16384 + k * 128 + n];
    else if (m == 8) v = root1[k * 128 + n];
    else if (m < 17) v = W2[(m - 9) * 16384 + k * 128 + n];
    else             v = root2[k * 128 + n];
    Wb[e] = f2bf(v);
}

// ---------------- static XCD-aware K-sliced gather + partial GEMM (slice-major X) ----------------
// Grid 1568. Block b: slice s = (b&7)>>1, tile = (b>>3)*2 + (b&1).
// Gather is STRAIGHT-LINE: 32 clamped srt loads + 32 unconditional X loads in one
// basic block (register block xd[8][4]) -> compiler pipelines all of them; the
// validity predicate becomes a mask-multiply in the accumulate. Rare deg>4 tails after.
__global__ __launch_bounds__(512) void k_gather(const unsigned short* __restrict__ Xs,
                                                const unsigned short* __restrict__ Wb,
                                                const int* __restrict__ off,
                                                const unsigned short* __restrict__ srt16,
                                                unsigned short* __restrict__ P,
                                                int row0)
{
    __shared__ unsigned short Al[8 * 64 * 40];   // 40 KB: plane stride 5120 B, row stride 80 B
    const int b = blockIdx.x;
    const int s = (b & 7) >> 1;
    const int tile = (b >> 3) * 2 + (b & 1);
    if (tile >= HT64) return;
    const int t = threadIdx.x;
    const int g = t >> 3, l8 = t & 7;            // gather: row / col-quad (4 bf16 each)
    const int lane = t & 63, w = t >> 6;
    const int rt = w >> 1, ch = w & 1;           // MFMA: 16-row tile / 64-col half
    const int cl = lane & 15, kq = lane >> 4;

    const unsigned short* Xt = Xs + (size_t)s * SL32;   // contiguous 3.2 MB slice table
    const int ks0 = s * 32;
    const int grow0 = row0 + tile * 64;

    // ---- gather: row grow0+g, slice cols; straight-line, mask-multiplied ----
    uint2 pk[8];
    const int row = grow0 + g;
    if (row < NN) {
        const int ob = row * 8;
        int4 q0 = *(const int4*)(off + ob);
        int4 q1 = *(const int4*)(off + ob + 4);
        int o8v = off[ob + 8];
        int o_[9] = {q0.x, q0.y, q0.z, q0.w, q1.x, q1.y, q1.z, q1.w, o8v};
        const unsigned short* Xp = Xt + l8 * 4;

        int cd[8];
        int idx[8][4];
        #pragma unroll
        for (int m = 0; m < 8; m++) {
            cd[m] = o_[m + 1] - o_[m];
            #pragma unroll
            for (int k = 0; k < 4; k++) {
                int e = o_[m] + k;
                idx[m][k] = (int)srt16[e < NE ? e : NE - 1];   // clamped, unconditional
            }
        }
        uint2 xd[8][4];
        #pragma unroll
        for (int m = 0; m < 8; m++)
            #pragma unroll
            for (int k = 0; k < 4; k++)
                xd[m][k] = *(const uint2*)(Xp + (size_t)idx[m][k] * 32);   // 32 independent loads

        float a[8][4];
        #pragma unroll
        for (int m = 0; m < 8; m++) {
            a[m][0] = a[m][1] = a[m][2] = a[m][3] = 0.f;
            #pragma unroll
            for (int k = 0; k < 4; k++) {
                float msk = (k < cd[m]) ? 1.f : 0.f;
                a[m][0] += msk * bflo(xd[m][k].x);
                a[m][1] += msk * bfhi(xd[m][k].x);
                a[m][2] += msk * bflo(xd[m][k].y);
                a[m][3] += msk * bfhi(xd[m][k].y);
            }
        }
        // rare tails (deg > 4): ~5% of buckets
        #pragma unroll
        for (int m = 0; m < 8; m++) {
            if (cd[m] > 4) {
                for (int k = 4; k < cd[m]; k++) {
                    int ii = (int)srt16[o_[m] + k];
                    uint2 uu = *(const uint2*)(Xp + (size_t)ii * 32);
                    a[m][0] += bflo(uu.x); a[m][1] += bfhi(uu.x);
                    a[m][2] += bflo(uu.y); a[m][3] += bfhi(uu.y);
                }
            }
        }
        #pragma unroll
        for (int m = 0; m < 8; m++) {
            float invc = 1.0f / (float)(cd[m] > 1 ? cd[m] : 1);
            pk[m].x = (unsigned int)f2bf(a[m][0] * invc) | ((unsigned int)f2bf(a[m][1] * invc) << 16);
            pk[m].y = (unsigned int)f2bf(a[m][2] * invc) | ((unsigned int)f2bf(a[m][3] * invc) << 16);
        }
    } else {
        #pragma unroll
        for (int m = 0; m < 8; m++) pk[m] = uint2{0u, 0u};
    }
    #pragma unroll
    for (int m = 0; m < 8; m++)
        *(uint2*)((char*)Al + m * 5120 + g * 80 + l8 * 8) = pk[m];
    __syncthreads();

    // ---- K=32 partial MFMA: 9 matrices, W direct from L2 ----
    f32x4 acc[4];
    #pragma unroll
    for (int ct = 0; ct < 4; ct++) acc[ct] = f32x4{0.f, 0.f, 0.f, 0.f};
    const int arow = rt * 16 + cl;
    #pragma unroll
    for (int m = 0; m < 8; m++) {
        short8 af = *(const short8*)((const char*)Al + m * 5120 + arow * 80 + kq * 16);
        #pragma unroll
        for (int ct = 0; ct < 4; ct++) {
            int n = ch * 64 + ct * 16 + cl;
            short8 bfr = *(const short8*)(Wb + (size_t)m * 16384 + n * 128 + ks0 + kq * 8);
            acc[ct] = __builtin_amdgcn_mfma_f32_16x16x32_bf16(af, bfr, acc[ct], 0, 0, 0);
        }
    }
    {   // root term: A from slice table
        int rg = grow0 + arow;
        short8 af = short8{0,0,0,0,0,0,0,0};
        if (rg < NN)
            af = *(const short8*)(Xt + (size_t)rg * 32 + kq * 8);
        #pragma unroll
        for (int ct = 0; ct < 4; ct++) {
            int n = ch * 64 + ct * 16 + cl;
            short8 bfr = *(const short8*)(Wb + (size_t)8 * 16384 + n * 128 + ks0 + kq * 8);
            acc[ct] = __builtin_amdgcn_mfma_f32_16x16x32_bf16(af, bfr, acc[ct], 0, 0, 0);
        }
    }

    // ---- store bf16 partial ----
    #pragma unroll
    for (int ct = 0; ct < 4; ct++) {
        int col = ch * 64 + ct * 16 + cl;
        #pragma unroll
        for (int j = 0; j < 4; j++) {
            int lrow = tile * 64 + rt * 16 + kq * 4 + j;
            P[((size_t)s * HROWS + lrow) * 128 + col] = f2bf(acc[ct][j]);
        }
    }
}

// ---------------- reduce 4 slice-partials + bias ----------------
// mode 0: relu -> SLICE-MAJOR bf16 (hs tables).  mode 1: L2-norm -> f32 out.
__global__ __launch_bounds__(256) void k_reduce(const unsigned short* __restrict__ P,
                                                const float* __restrict__ bias,
                                                unsigned short* __restrict__ out_sl,
                                                float* __restrict__ out_f,
                                                int row0, int mode)
{
    int lr = blockIdx.x * 4 + (threadIdx.x >> 6);
    int row = row0 + lr;
    if (lr >= HROWS || row >= NN) return;
    int lane = threadIdx.x & 63;
    int col = lane * 2;
    float sx = 0.f, sy = 0.f;
    #pragma unroll
    for (int s = 0; s < 4; s++) {
        unsigned int u = *(const unsigned int*)(P + ((size_t)s * HROWS + lr) * 128 + col);
        sx += bflo(u); sy += bfhi(u);
    }
    float2 bb = *(const float2*)(bias + col);
    sx += bb.x; sy += bb.y;
    if (mode == 0) {
        sx = fmaxf(sx, 0.f); sy = fmaxf(sy, 0.f);
        unsigned int o = (unsigned int)f2bf(sx) | ((unsigned int)f2bf(sy) << 16);
        int s = lane >> 4;                       // slice of these 2 cols
        *(unsigned int*)(out_sl + (size_t)s * SL32 + (size_t)row * 32 + (lane & 15) * 2) = o;
    } else {
        float ss = sx * sx + sy * sy;
        #pragma unroll
        for (int o = 32; o > 0; o >>= 1) ss += __shfl_xor(ss, o);
        float inv = 1.0f / fmaxf(sqrtf(ss), 1e-12f);
        float2 o2; o2.x = sx * inv; o2.y = sy * inv;
        *(float2*)(out_f + (size_t)row * 128 + col) = o2;
    }
}

extern "C" void kernel_launch(void* const* d_in, const int* in_sizes, int n_in,
                              void* d_out, int out_size, void* d_ws, size_t ws_size,
                              hipStream_t stream)
{
    const float* x     = (const float*)d_in[0];
    const int*   ei    = (const int*)d_in[1];   // [2, E]
    const int*   et    = (const int*)d_in[2];   // [E]
    const float* W1    = (const float*)d_in[3];
    const float* root1 = (const float*)d_in[4];
    const float* b1    = (const float*)d_in[5];
    const float* W2    = (const float*)d_in[6];
    const float* root2 = (const float*)d_in[7];
    const float* b2    = (const float*)d_in[8];
    float* out = (float*)d_out;

    char* ws = (char*)d_ws;
    int* cnt   = (int*)ws;                                  // MB ints
    int* off   = cnt + MB;                                  // MB+1 ints
    int* bsum  = off + MB + 1;                              // 256
    int* carry = bsum + 256;                                // 256
    unsigned short* rank16 = (unsigned short*)(carry + 256);        // NE u16
    unsigned short* srt16  = rank16 + NE;                           // NE u16
    unsigned short* Xs     = srt16 + NE;                            // 4 slice tables (12.8 MB)
    unsigned short* hs     = Xs + (size_t)NN * DD;                  // 4 slice tables (12.8 MB)
    unsigned short* Wb     = hs + (size_t)NN * DD;                  // 18*16384 bf16
    unsigned short* P      = Wb + (size_t)18 * 16384;               // 4*HROWS*128 bf16 (25.6 MB)

    hipMemsetAsync(cnt, 0, (size_t)MB * 4, stream);

    k_count<<<(NE + 255) / 256, 256, 0, stream>>>(ei, et, cnt, rank16);
    k_scan1<<<NBLK, 256, 0, stream>>>(cnt, off, bsum);
    k_scan2<<<1, 256, 0, stream>>>(bsum, carry);
    k_scan3<<<NBLK, 256, 0, stream>>>(off, carry);
    k_place<<<(NE + 255) / 256, 256, 0, stream>>>(ei, et, off, rank16, srt16);

    k_tobf16s<<<(NN * 32 + 255) / 256, 256, 0, stream>>>(x, Xs);
    k_wconv<<<(18 * 16384 + 255) / 256, 256, 0, stream>>>(W1, root1, W2, root2, Wb);

    const int g_grid = 1568;              // 196 q-steps x 8 (4 slices x 2 tile-lanes)
    const int r_grid = (HROWS + 3) / 4;   // 6256

    // ---- layer 1: hs = relu(x@root1 + b1 + sum_r mean_r(x)@W1r), slice-major ----
    for (int h = 0; h < 2; h++) {
        k_gather<<<g_grid, 512, 0, stream>>>(Xs, Wb, off, srt16, P, h * HROWS);
        k_reduce<<<r_grid, 256, 0, stream>>>(P, b1, hs, nullptr, h * HROWS, 0);
    }
    // ---- layer 2: out = normalize(hs@root2 + b2 + sum_r mean_r(hs)@W2r) ----
    for (int h = 0; h < 2; h++) {
        k_gather<<<g_grid, 512, 0, stream>>>(hs, Wb + (size_t)9 * 16384, off, srt16, P, h * HROWS);
        k_reduce<<<r_grid, 256, 0, stream>>>(P, b2, nullptr, out, h * HROWS, 1);
    }
}